// Round 1
// baseline (767.331 us; speedup 1.0000x reference)
//
#include <hip/hip_runtime.h>

// Problem constants (from reference setup_inputs)
constexpr int NN = 50000;   // nodes
constexpr int H  = 128;     // hidden
constexpr int F  = 256;     // input features
constexpr int C  = 40;      // classes

// ---------------------------------------------------------------- utilities
__global__ void zero_ints(int* __restrict__ p, int n) {
    int i = blockIdx.x * blockDim.x + threadIdx.x;
    if (i < n) p[i] = 0;
}

__global__ void count_deg(const int* __restrict__ src, const int* __restrict__ dst,
                          int* __restrict__ cnt_out, int* __restrict__ cnt_in, int E) {
    int e = blockIdx.x * blockDim.x + threadIdx.x;
    if (e < E) {
        atomicAdd(&cnt_out[src[e]], 1);
        atomicAdd(&cnt_in[dst[e]], 1);
    }
}

__global__ void make_rs(const int* __restrict__ cnt_out, const int* __restrict__ cnt_in,
                        float* __restrict__ rs_out, float* __restrict__ rs_in, int n) {
    int i = blockIdx.x * blockDim.x + threadIdx.x;
    if (i < n) {
        rs_out[i] = rsqrtf((float)max(cnt_out[i], 1));
        rs_in[i]  = rsqrtf((float)max(cnt_in[i], 1));
    }
}

// single-block exclusive prefix sum over n<=256*chunk entries
__global__ void scan_block(const int* __restrict__ cnt, int* __restrict__ row_start, int n) {
    __shared__ int partial[256];
    int t = threadIdx.x;
    int chunk = (n + 255) / 256;
    int begin = t * chunk;
    int end   = min(begin + chunk, n);
    int s = 0;
    for (int i = begin; i < end; i++) s += cnt[i];
    partial[t] = s;
    __syncthreads();
    // Hillis-Steele inclusive scan over 256 partials
    for (int off = 1; off < 256; off <<= 1) {
        int v = (t >= off) ? partial[t - off] : 0;
        __syncthreads();
        partial[t] += v;
        __syncthreads();
    }
    int run = (t > 0) ? partial[t - 1] : 0;
    for (int i = begin; i < end; i++) {
        row_start[i] = run;
        run += cnt[i];
    }
}

__global__ void fill_csr(const int* __restrict__ src, const int* __restrict__ dst,
                         const int* __restrict__ row_start, int* __restrict__ cursor,
                         int* __restrict__ csr_src, int E) {
    int e = blockIdx.x * blockDim.x + threadIdx.x;
    if (e < E) {
        int d = dst[e];
        int pos = row_start[d] + atomicAdd(&cursor[d], 1);
        csr_src[pos] = src[e];
    }
}

// ---------------------------------------------------------------- SGEMM
// C[M,N] = A[M,K] @ B[K,N]  (row-major), epilogue:
//   if row_scale: *= row_scale[row]   (applied before bias)
//   if bias:      += bias[col]
template<int BM, int BN, int BK, int TM, int TN>
__global__ __launch_bounds__(256) void sgemm_ep(
        const float* __restrict__ A, const float* __restrict__ B,
        const float* __restrict__ bias, const float* __restrict__ row_scale,
        float* __restrict__ Cmat, int M, int N, int K) {
    __shared__ float As[BK][BM + 1];
    __shared__ float Bs[BK][BN + 1];
    const int tid = threadIdx.x;
    const int nthx = BN / TN;                 // 16
    const int tx = tid % nthx;
    const int ty = tid / nthx;
    const int row0 = blockIdx.y * BM;
    const int col0 = blockIdx.x * BN;

    float acc[TM][TN];
#pragma unroll
    for (int i = 0; i < TM; i++)
#pragma unroll
        for (int j = 0; j < TN; j++) acc[i][j] = 0.f;

    for (int k0 = 0; k0 < K; k0 += BK) {
        // A tile: BM x BK, stored transposed As[k][m]
        for (int i = tid; i < BM * BK; i += 256) {
            int m = i / BK, kk = i % BK;
            int gr = row0 + m;
            As[kk][m] = (gr < M) ? A[(long)gr * K + k0 + kk] : 0.f;
        }
        // B tile: BK x BN
        for (int i = tid; i < BK * BN; i += 256) {
            int kk = i / BN, n = i % BN;
            int gc = col0 + n;
            Bs[kk][n] = (gc < N) ? B[(long)(k0 + kk) * N + gc] : 0.f;
        }
        __syncthreads();
#pragma unroll
        for (int kk = 0; kk < BK; kk++) {
            float a[TM], b[TN];
#pragma unroll
            for (int i = 0; i < TM; i++) a[i] = As[kk][ty * TM + i];
#pragma unroll
            for (int j = 0; j < TN; j++) b[j] = Bs[kk][tx * TN + j];
#pragma unroll
            for (int i = 0; i < TM; i++)
#pragma unroll
                for (int j = 0; j < TN; j++) acc[i][j] += a[i] * b[j];
        }
        __syncthreads();
    }

#pragma unroll
    for (int i = 0; i < TM; i++) {
        int gr = row0 + ty * TM + i;
        if (gr >= M) continue;
        float rs = row_scale ? row_scale[gr] : 1.f;
#pragma unroll
        for (int j = 0; j < TN; j++) {
            int gc = col0 + tx * TN + j;
            if (gc < N) {
                float v = acc[i][j] * rs;
                if (bias) v += bias[gc];
                Cmat[(long)gr * N + gc] = v;
            }
        }
    }
}

// ---------------------------------------------------------------- aggregation
// out[v,:] = relu( rs_in[v] * sum_{s in row(v)} h[s,:] + bias[:] )
// one 128-thread block per dst node; h rows already scaled by rs_out.
__global__ __launch_bounds__(128) void aggregate(
        const float* __restrict__ h, const int* __restrict__ csr_src,
        const int* __restrict__ row_start, const int* __restrict__ cnt_in,
        const float* __restrict__ rs_in, const float* __restrict__ bias,
        float* __restrict__ out) {
    int v = blockIdx.x;
    int t = threadIdx.x;           // 0..127 = feature index
    int s0 = row_start[v];
    int cnt = cnt_in[v];
    float acc = 0.f;
    for (int i = 0; i < cnt; i++) {
        int s = csr_src[s0 + i];
        acc += h[(long)s * H + t];
    }
    float m = acc * rs_in[v] + bias[t];
    out[(long)v * H + t] = fmaxf(m, 0.f);
}

// ---------------------------------------------------------------- launch
extern "C" void kernel_launch(void* const* d_in, const int* in_sizes, int n_in,
                              void* d_out, int out_size, void* d_ws, size_t ws_size,
                              hipStream_t stream) {
    const float* n_feats = (const float*)d_in[0];
    const int*   src     = (const int*)d_in[1];
    const int*   dst     = (const int*)d_in[2];
    const float* Wp      = (const float*)d_in[3];
    const float* bp      = (const float*)d_in[4];
    const float* W1      = (const float*)d_in[5];
    const float* b1      = (const float*)d_in[6];
    const float* W2      = (const float*)d_in[7];
    const float* b2      = (const float*)d_in[8];
    const float* Wc      = (const float*)d_in[9];
    const float* bc      = (const float*)d_in[10];
    float* out = (float*)d_out;
    const int E = in_sizes[1];

    // workspace layout (all 4-byte types)
    char* ws = (char*)d_ws;
    int*   cnt_out   = (int*)ws;                       // N
    int*   cnt_in    = cnt_out + NN;                   // N
    int*   cursor    = cnt_in + NN;                    // N
    int*   row_start = cursor + NN;                    // N
    float* rs_out    = (float*)(row_start + NN);       // N
    float* rs_in     = rs_out + NN;                    // N
    int*   csr_src   = (int*)(rs_in + NN);             // E
    float* xbuf      = (float*)(csr_src + E);          // N*H
    float* hbuf      = xbuf + (long)NN * H;            // N*H

    const int TB = 256;
    // 1. zero counters (cnt_out, cnt_in, cursor are contiguous)
    zero_ints<<<(3 * NN + TB - 1) / TB, TB, 0, stream>>>(cnt_out, 3 * NN);
    // 2. degrees
    count_deg<<<(E + TB - 1) / TB, TB, 0, stream>>>(src, dst, cnt_out, cnt_in, E);
    // 3. rsqrt norms
    make_rs<<<(NN + TB - 1) / TB, TB, 0, stream>>>(cnt_out, cnt_in, rs_out, rs_in, NN);
    // 4. CSR row starts (by dst)
    scan_block<<<1, 256, 0, stream>>>(cnt_in, row_start, NN);
    // 5. CSR fill
    fill_csr<<<(E + TB - 1) / TB, TB, 0, stream>>>(src, dst, row_start, cursor, csr_src, E);

    // 6. projection: xbuf = n_feats @ Wp + bp       [NN,256]x[256,128]
    {
        dim3 grid(H / 128, (NN + 127) / 128);
        sgemm_ep<128, 128, 8, 8, 8><<<grid, 256, 0, stream>>>(
            n_feats, Wp, bp, nullptr, xbuf, NN, H, F);
    }
    // 7. layer 1: hbuf = (xbuf @ W1) * rs_out
    {
        dim3 grid(H / 128, (NN + 127) / 128);
        sgemm_ep<128, 128, 8, 8, 8><<<grid, 256, 0, stream>>>(
            xbuf, W1, nullptr, rs_out, hbuf, NN, H, H);
    }
    // 8. aggregate -> xbuf = relu(rs_in * (A hbuf) + b1)
    aggregate<<<NN, 128, 0, stream>>>(hbuf, csr_src, row_start, cnt_in, rs_in, b1, xbuf);
    // 9. layer 2
    {
        dim3 grid(H / 128, (NN + 127) / 128);
        sgemm_ep<128, 128, 8, 8, 8><<<grid, 256, 0, stream>>>(
            xbuf, W2, nullptr, rs_out, hbuf, NN, H, H);
    }
    // 10. aggregate -> xbuf = relu(rs_in * (A hbuf) + b2)
    aggregate<<<NN, 128, 0, stream>>>(hbuf, csr_src, row_start, cnt_in, rs_in, b2, xbuf);
    // 11. classifier: out = xbuf @ Wc + bc          [NN,128]x[128,40]
    {
        dim3 grid((C + 63) / 64, (NN + 63) / 64);
        sgemm_ep<64, 64, 16, 4, 4><<<grid, 256, 0, stream>>>(
            xbuf, Wc, bc, nullptr, out, NN, C, H);
    }
}

// Round 2
// 554.516 us; speedup vs baseline: 1.3838x; 1.3838x over previous
//
#include <hip/hip_runtime.h>

// Problem constants (from reference setup_inputs)
constexpr int NN = 50000;   // nodes
constexpr int H  = 128;     // hidden
constexpr int F  = 256;     // input features
constexpr int C  = 40;      // classes

// ---------------------------------------------------------------- utilities
__global__ void zero_ints(int* __restrict__ p, int n) {
    int i = blockIdx.x * blockDim.x + threadIdx.x;
    if (i < n) p[i] = 0;
}

__global__ void count_deg(const int* __restrict__ src, const int* __restrict__ dst,
                          int* __restrict__ cnt_out, int* __restrict__ cnt_in, int E) {
    int e = blockIdx.x * blockDim.x + threadIdx.x;
    if (e < E) {
        atomicAdd(&cnt_out[src[e]], 1);
        atomicAdd(&cnt_in[dst[e]], 1);
    }
}

__global__ void make_rs(const int* __restrict__ cnt_out, const int* __restrict__ cnt_in,
                        float* __restrict__ rs_out, float* __restrict__ rs_in, int n) {
    int i = blockIdx.x * blockDim.x + threadIdx.x;
    if (i < n) {
        rs_out[i] = rsqrtf((float)max(cnt_out[i], 1));
        rs_in[i]  = rsqrtf((float)max(cnt_in[i], 1));
    }
}

// single-block exclusive prefix sum
__global__ void scan_block(const int* __restrict__ cnt, int* __restrict__ row_start, int n) {
    __shared__ int partial[256];
    int t = threadIdx.x;
    int chunk = (n + 255) / 256;
    int begin = t * chunk;
    int end   = min(begin + chunk, n);
    int s = 0;
    for (int i = begin; i < end; i++) s += cnt[i];
    partial[t] = s;
    __syncthreads();
    for (int off = 1; off < 256; off <<= 1) {
        int v = (t >= off) ? partial[t - off] : 0;
        __syncthreads();
        partial[t] += v;
        __syncthreads();
    }
    int run = (t > 0) ? partial[t - 1] : 0;
    for (int i = begin; i < end; i++) {
        row_start[i] = run;
        run += cnt[i];
    }
}

__global__ void fill_csr(const int* __restrict__ src, const int* __restrict__ dst,
                         const int* __restrict__ row_start, int* __restrict__ cursor,
                         int* __restrict__ csr_src, int E) {
    int e = blockIdx.x * blockDim.x + threadIdx.x;
    if (e < E) {
        int d = dst[e];
        int pos = row_start[d] + atomicAdd(&cursor[d], 1);
        csr_src[pos] = src[e];
    }
}

// ---------------------------------------------------------------- main SGEMM
// C[M,N] = A[M,K] @ B[K,N], row-major. Requires N % 64 == 0, K % 32 == 0.
// Tile: BM=128, BN=64, BK=32; 256 threads; micro-tile 8x4.
// Epilogue: optional row_scale[row] then optional bias[col].
__global__ __launch_bounds__(256) void sgemm_big(
        const float* __restrict__ A, const float* __restrict__ B,
        const float* __restrict__ bias, const float* __restrict__ row_scale,
        float* __restrict__ Cmat, int M, int N, int K) {
    constexpr int BM = 128, BN = 64, BK = 32;
    // pads chosen for 16B alignment + conflict-free inner reads
    __shared__ __align__(16) float As[BK][132];   // [k][m]
    __shared__ __align__(16) float Bs[BK][68];    // [k][n]

    const int tid  = threadIdx.x;
    const int tx   = tid & 15;          // 0..15 -> col group
    const int ty   = tid >> 4;          // 0..15 -> row group
    const int row0 = blockIdx.y * BM;
    const int col0 = blockIdx.x * BN;

    // A-load mapping: 8 float4 per row, 32 rows per pass, 4 passes
    const int a_k4  = tid & 7;          // float4 index along K
    const int a_row = tid >> 3;         // 0..31
    // B-load mapping: 16 float4 per row, 16 k-rows per pass, 2 passes
    const int b_c4  = tid & 15;
    const int b_k   = tid >> 4;         // 0..15

    float acc[8][4];
#pragma unroll
    for (int i = 0; i < 8; i++)
#pragma unroll
        for (int j = 0; j < 4; j++) acc[i][j] = 0.f;

    for (int k0 = 0; k0 < K; k0 += BK) {
        // stage A tile (BM x BK), store transposed As[k][m]
#pragma unroll
        for (int r = 0; r < 4; r++) {
            int m  = a_row + 32 * r;
            int gr = row0 + m;
            float4 v = make_float4(0.f, 0.f, 0.f, 0.f);
            if (gr < M)
                v = *(const float4*)&A[(long)gr * K + k0 + a_k4 * 4];
            As[a_k4 * 4 + 0][m] = v.x;
            As[a_k4 * 4 + 1][m] = v.y;
            As[a_k4 * 4 + 2][m] = v.z;
            As[a_k4 * 4 + 3][m] = v.w;
        }
        // stage B tile (BK x BN)
#pragma unroll
        for (int r = 0; r < 2; r++) {
            int kk = b_k + 16 * r;
            float4 v = *(const float4*)&B[(long)(k0 + kk) * N + col0 + b_c4 * 4];
            *(float4*)&Bs[kk][b_c4 * 4] = v;
        }
        __syncthreads();

#pragma unroll
        for (int kk = 0; kk < BK; kk++) {
            float4 a0 = *(const float4*)&As[kk][ty * 8];
            float4 a1 = *(const float4*)&As[kk][ty * 8 + 4];
            float4 b0 = *(const float4*)&Bs[kk][tx * 4];
            const float a[8] = {a0.x, a0.y, a0.z, a0.w, a1.x, a1.y, a1.z, a1.w};
            const float b[4] = {b0.x, b0.y, b0.z, b0.w};
#pragma unroll
            for (int i = 0; i < 8; i++)
#pragma unroll
                for (int j = 0; j < 4; j++) acc[i][j] += a[i] * b[j];
        }
        __syncthreads();
    }

#pragma unroll
    for (int i = 0; i < 8; i++) {
        int gr = row0 + ty * 8 + i;
        if (gr >= M) continue;
        float rs = row_scale ? row_scale[gr] : 1.f;
        float4 v;
        v.x = acc[i][0] * rs; v.y = acc[i][1] * rs;
        v.z = acc[i][2] * rs; v.w = acc[i][3] * rs;
        if (bias) {
            const float4 bb = *(const float4*)&bias[col0 + tx * 4];
            v.x += bb.x; v.y += bb.y; v.z += bb.z; v.w += bb.w;
        }
        *(float4*)&Cmat[(long)gr * N + col0 + tx * 4] = v;
    }
}

// ---------------------------------------------------------------- small SGEMM (classifier)
template<int BM, int BN, int BK, int TM, int TN>
__global__ __launch_bounds__(256) void sgemm_ep(
        const float* __restrict__ A, const float* __restrict__ B,
        const float* __restrict__ bias, const float* __restrict__ row_scale,
        float* __restrict__ Cmat, int M, int N, int K) {
    __shared__ float As[BK][BM + 1];
    __shared__ float Bs[BK][BN + 1];
    const int tid = threadIdx.x;
    const int nthx = BN / TN;
    const int tx = tid % nthx;
    const int ty = tid / nthx;
    const int row0 = blockIdx.y * BM;
    const int col0 = blockIdx.x * BN;

    float acc[TM][TN];
#pragma unroll
    for (int i = 0; i < TM; i++)
#pragma unroll
        for (int j = 0; j < TN; j++) acc[i][j] = 0.f;

    for (int k0 = 0; k0 < K; k0 += BK) {
        for (int i = tid; i < BM * BK; i += 256) {
            int m = i / BK, kk = i % BK;
            int gr = row0 + m;
            As[kk][m] = (gr < M) ? A[(long)gr * K + k0 + kk] : 0.f;
        }
        for (int i = tid; i < BK * BN; i += 256) {
            int kk = i / BN, n = i % BN;
            int gc = col0 + n;
            Bs[kk][n] = (gc < N) ? B[(long)(k0 + kk) * N + gc] : 0.f;
        }
        __syncthreads();
#pragma unroll
        for (int kk = 0; kk < BK; kk++) {
            float a[TM], b[TN];
#pragma unroll
            for (int i = 0; i < TM; i++) a[i] = As[kk][ty * TM + i];
#pragma unroll
            for (int j = 0; j < TN; j++) b[j] = Bs[kk][tx * TN + j];
#pragma unroll
            for (int i = 0; i < TM; i++)
#pragma unroll
                for (int j = 0; j < TN; j++) acc[i][j] += a[i] * b[j];
        }
        __syncthreads();
    }

#pragma unroll
    for (int i = 0; i < TM; i++) {
        int gr = row0 + ty * TM + i;
        if (gr >= M) continue;
        float rs = row_scale ? row_scale[gr] : 1.f;
#pragma unroll
        for (int j = 0; j < TN; j++) {
            int gc = col0 + tx * TN + j;
            if (gc < N) {
                float v = acc[i][j] * rs;
                if (bias) v += bias[gc];
                Cmat[(long)gr * N + gc] = v;
            }
        }
    }
}

// ---------------------------------------------------------------- aggregation
// out[v,:] = relu( rs_in[v] * sum_{s in row(v)} h[s,:] + bias[:] )
// One wave per node, lane = float2 of the 128-wide feature row.
__global__ __launch_bounds__(256) void aggregate(
        const float* __restrict__ h, const int* __restrict__ csr_src,
        const int* __restrict__ row_start, const int* __restrict__ cnt_in,
        const float* __restrict__ rs_in, const float* __restrict__ bias,
        float* __restrict__ out, int nodes) {
    const int wave = threadIdx.x >> 6;
    const int lane = threadIdx.x & 63;
    const int v = blockIdx.x * 4 + wave;
    if (v >= nodes) return;
    const float2* __restrict__ h2 = (const float2*)h;
    const int s0  = row_start[v];
    const int cnt = cnt_in[v];
    float ax = 0.f, ay = 0.f;
    int i = 0;
    for (; i + 4 <= cnt; i += 4) {
        int sa = csr_src[s0 + i];
        int sb = csr_src[s0 + i + 1];
        int sc = csr_src[s0 + i + 2];
        int sd = csr_src[s0 + i + 3];
        float2 va = h2[(long)sa * 64 + lane];
        float2 vb = h2[(long)sb * 64 + lane];
        float2 vc = h2[(long)sc * 64 + lane];
        float2 vd = h2[(long)sd * 64 + lane];
        ax += (va.x + vb.x) + (vc.x + vd.x);
        ay += (va.y + vb.y) + (vc.y + vd.y);
    }
    for (; i < cnt; i++) {
        int s = csr_src[s0 + i];
        float2 vv = h2[(long)s * 64 + lane];
        ax += vv.x; ay += vv.y;
    }
    const float rs = rs_in[v];
    const float2 bb = ((const float2*)bias)[lane];
    float2 o;
    o.x = fmaxf(ax * rs + bb.x, 0.f);
    o.y = fmaxf(ay * rs + bb.y, 0.f);
    ((float2*)out)[(long)v * 64 + lane] = o;
}

// ---------------------------------------------------------------- launch
extern "C" void kernel_launch(void* const* d_in, const int* in_sizes, int n_in,
                              void* d_out, int out_size, void* d_ws, size_t ws_size,
                              hipStream_t stream) {
    const float* n_feats = (const float*)d_in[0];
    const int*   src     = (const int*)d_in[1];
    const int*   dst     = (const int*)d_in[2];
    const float* Wp      = (const float*)d_in[3];
    const float* bp      = (const float*)d_in[4];
    const float* W1      = (const float*)d_in[5];
    const float* b1      = (const float*)d_in[6];
    const float* W2      = (const float*)d_in[7];
    const float* b2      = (const float*)d_in[8];
    const float* Wc      = (const float*)d_in[9];
    const float* bc      = (const float*)d_in[10];
    float* out = (float*)d_out;
    const int E = in_sizes[1];

    // workspace layout (all 4-byte types)
    char* ws = (char*)d_ws;
    int*   cnt_out   = (int*)ws;                       // N
    int*   cnt_in    = cnt_out + NN;                   // N
    int*   cursor    = cnt_in + NN;                    // N
    int*   row_start = cursor + NN;                    // N
    float* rs_out    = (float*)(row_start + NN);       // N
    float* rs_in     = rs_out + NN;                    // N
    int*   csr_src   = (int*)(rs_in + NN);             // E
    float* xbuf      = (float*)(csr_src + E);          // N*H
    float* hbuf      = xbuf + (long)NN * H;            // N*H

    const int TB = 256;
    zero_ints<<<(3 * NN + TB - 1) / TB, TB, 0, stream>>>(cnt_out, 3 * NN);
    count_deg<<<(E + TB - 1) / TB, TB, 0, stream>>>(src, dst, cnt_out, cnt_in, E);
    make_rs<<<(NN + TB - 1) / TB, TB, 0, stream>>>(cnt_out, cnt_in, rs_out, rs_in, NN);
    scan_block<<<1, 256, 0, stream>>>(cnt_in, row_start, NN);
    fill_csr<<<(E + TB - 1) / TB, TB, 0, stream>>>(src, dst, row_start, cursor, csr_src, E);

    const dim3 gbig(H / 64, (NN + 127) / 128);   // (2, 391)
    // 6. projection: xbuf = n_feats @ Wp + bp
    sgemm_big<<<gbig, 256, 0, stream>>>(n_feats, Wp, bp, nullptr, xbuf, NN, H, F);
    // 7. layer 1 GEMM: hbuf = (xbuf @ W1) * rs_out
    sgemm_big<<<gbig, 256, 0, stream>>>(xbuf, W1, nullptr, rs_out, hbuf, NN, H, H);
    // 8. aggregate: xbuf = relu(rs_in * (A hbuf) + b1)
    aggregate<<<(NN + 3) / 4, 256, 0, stream>>>(hbuf, csr_src, row_start, cnt_in, rs_in, b1, xbuf, NN);
    // 9. layer 2 GEMM
    sgemm_big<<<gbig, 256, 0, stream>>>(xbuf, W2, nullptr, rs_out, hbuf, NN, H, H);
    // 10. aggregate
    aggregate<<<(NN + 3) / 4, 256, 0, stream>>>(hbuf, csr_src, row_start, cnt_in, rs_in, b2, xbuf, NN);
    // 11. classifier: out = xbuf @ Wc + bc
    {
        dim3 grid((C + 63) / 64, (NN + 63) / 64);
        sgemm_ep<64, 64, 16, 4, 4><<<grid, 256, 0, stream>>>(xbuf, Wc, bc, nullptr, out, NN, C, H);
    }
}

// Round 3
// 480.116 us; speedup vs baseline: 1.5982x; 1.1550x over previous
//
#include <hip/hip_runtime.h>

// Problem constants (from reference setup_inputs)
constexpr int NN = 50000;   // nodes
constexpr int H  = 128;     // hidden
constexpr int F  = 256;     // input features
constexpr int C  = 40;      // classes

// ---------------------------------------------------------------- utilities
__global__ void zero_ints(int* __restrict__ p, int n) {
    int i = blockIdx.x * blockDim.x + threadIdx.x;
    if (i < n) p[i] = 0;
}

__global__ void count_deg(const int* __restrict__ src, const int* __restrict__ dst,
                          int* __restrict__ cnt_out, int* __restrict__ cnt_in, int E) {
    int e = blockIdx.x * blockDim.x + threadIdx.x;
    if (e < E) {
        atomicAdd(&cnt_out[src[e]], 1);
        atomicAdd(&cnt_in[dst[e]], 1);
    }
}

__global__ void make_rs(const int* __restrict__ cnt_out, const int* __restrict__ cnt_in,
                        float* __restrict__ rs_out, float* __restrict__ rs_in, int n) {
    int i = blockIdx.x * blockDim.x + threadIdx.x;
    if (i < n) {
        rs_out[i] = rsqrtf((float)max(cnt_out[i], 1));
        rs_in[i]  = rsqrtf((float)max(cnt_in[i], 1));
    }
}

// ------------------------------------------------ parallel exclusive scan
// Phase 1: per-block exclusive scan (256 elements/block) + block totals.
__global__ __launch_bounds__(256) void scan_partial(
        const int* __restrict__ cnt, int* __restrict__ excl,
        int* __restrict__ block_sums, int n) {
    __shared__ int sh[256];
    const int t = threadIdx.x;
    const int i = blockIdx.x * 256 + t;
    const int v = (i < n) ? cnt[i] : 0;
    sh[t] = v;
    __syncthreads();
    // Hillis-Steele inclusive scan
#pragma unroll
    for (int off = 1; off < 256; off <<= 1) {
        int u = (t >= off) ? sh[t - off] : 0;
        __syncthreads();
        sh[t] += u;
        __syncthreads();
    }
    if (i < n) excl[i] = sh[t] - v;   // exclusive within block
    if (t == 255) block_sums[blockIdx.x] = sh[255];
}

// Phase 2: single small block turns block_sums into exclusive offsets (nb<=256).
__global__ __launch_bounds__(256) void scan_sums(int* __restrict__ block_sums, int nb) {
    __shared__ int sh[256];
    const int t = threadIdx.x;
    const int v = (t < nb) ? block_sums[t] : 0;
    sh[t] = v;
    __syncthreads();
#pragma unroll
    for (int off = 1; off < 256; off <<= 1) {
        int u = (t >= off) ? sh[t - off] : 0;
        __syncthreads();
        sh[t] += u;
        __syncthreads();
    }
    if (t < nb) block_sums[t] = sh[t] - v;  // exclusive
}

// Phase 3: add block offsets.
__global__ __launch_bounds__(256) void scan_add(
        int* __restrict__ row_start, const int* __restrict__ block_sums, int n) {
    const int i = blockIdx.x * 256 + threadIdx.x;
    if (i < n) row_start[i] += block_sums[blockIdx.x];
}

__global__ void fill_csr(const int* __restrict__ src, const int* __restrict__ dst,
                         const int* __restrict__ row_start, int* __restrict__ cursor,
                         int* __restrict__ csr_src, int E) {
    int e = blockIdx.x * blockDim.x + threadIdx.x;
    if (e < E) {
        int d = dst[e];
        int pos = row_start[d] + atomicAdd(&cursor[d], 1);
        csr_src[pos] = src[e];
    }
}

// ---------------------------------------------------------------- main SGEMM
// C[M,N] = A[M,K] @ B[K,N], row-major. Requires N % 64 == 0, K % 32 == 0.
// Tile: BM=128, BN=64, BK=32; 256 threads; micro-tile 8x4.
__global__ __launch_bounds__(256) void sgemm_big(
        const float* __restrict__ A, const float* __restrict__ B,
        const float* __restrict__ bias, const float* __restrict__ row_scale,
        float* __restrict__ Cmat, int M, int N, int K) {
    constexpr int BM = 128, BN = 64, BK = 32;
    __shared__ __align__(16) float As[BK][132];   // [k][m]
    __shared__ __align__(16) float Bs[BK][68];    // [k][n]

    const int tid  = threadIdx.x;
    const int tx   = tid & 15;
    const int ty   = tid >> 4;
    const int row0 = blockIdx.y * BM;
    const int col0 = blockIdx.x * BN;

    const int a_k4  = tid & 7;
    const int a_row = tid >> 3;
    const int b_c4  = tid & 15;
    const int b_k   = tid >> 4;

    float acc[8][4];
#pragma unroll
    for (int i = 0; i < 8; i++)
#pragma unroll
        for (int j = 0; j < 4; j++) acc[i][j] = 0.f;

    for (int k0 = 0; k0 < K; k0 += BK) {
#pragma unroll
        for (int r = 0; r < 4; r++) {
            int m  = a_row + 32 * r;
            int gr = row0 + m;
            float4 v = make_float4(0.f, 0.f, 0.f, 0.f);
            if (gr < M)
                v = *(const float4*)&A[(long)gr * K + k0 + a_k4 * 4];
            As[a_k4 * 4 + 0][m] = v.x;
            As[a_k4 * 4 + 1][m] = v.y;
            As[a_k4 * 4 + 2][m] = v.z;
            As[a_k4 * 4 + 3][m] = v.w;
        }
#pragma unroll
        for (int r = 0; r < 2; r++) {
            int kk = b_k + 16 * r;
            float4 v = *(const float4*)&B[(long)(k0 + kk) * N + col0 + b_c4 * 4];
            *(float4*)&Bs[kk][b_c4 * 4] = v;
        }
        __syncthreads();

#pragma unroll
        for (int kk = 0; kk < BK; kk++) {
            float4 a0 = *(const float4*)&As[kk][ty * 8];
            float4 a1 = *(const float4*)&As[kk][ty * 8 + 4];
            float4 b0 = *(const float4*)&Bs[kk][tx * 4];
            const float a[8] = {a0.x, a0.y, a0.z, a0.w, a1.x, a1.y, a1.z, a1.w};
            const float b[4] = {b0.x, b0.y, b0.z, b0.w};
#pragma unroll
            for (int i = 0; i < 8; i++)
#pragma unroll
                for (int j = 0; j < 4; j++) acc[i][j] += a[i] * b[j];
        }
        __syncthreads();
    }

#pragma unroll
    for (int i = 0; i < 8; i++) {
        int gr = row0 + ty * 8 + i;
        if (gr >= M) continue;
        float rs = row_scale ? row_scale[gr] : 1.f;
        float4 v;
        v.x = acc[i][0] * rs; v.y = acc[i][1] * rs;
        v.z = acc[i][2] * rs; v.w = acc[i][3] * rs;
        if (bias) {
            const float4 bb = *(const float4*)&bias[col0 + tx * 4];
            v.x += bb.x; v.y += bb.y; v.z += bb.z; v.w += bb.w;
        }
        *(float4*)&Cmat[(long)gr * N + col0 + tx * 4] = v;
    }
}

// ---------------------------------------------------------------- small SGEMM (classifier)
template<int BM, int BN, int BK, int TM, int TN>
__global__ __launch_bounds__(256) void sgemm_ep(
        const float* __restrict__ A, const float* __restrict__ B,
        const float* __restrict__ bias, const float* __restrict__ row_scale,
        float* __restrict__ Cmat, int M, int N, int K) {
    __shared__ float As[BK][BM + 1];
    __shared__ float Bs[BK][BN + 1];
    const int tid = threadIdx.x;
    const int nthx = BN / TN;
    const int tx = tid % nthx;
    const int ty = tid / nthx;
    const int row0 = blockIdx.y * BM;
    const int col0 = blockIdx.x * BN;

    float acc[TM][TN];
#pragma unroll
    for (int i = 0; i < TM; i++)
#pragma unroll
        for (int j = 0; j < TN; j++) acc[i][j] = 0.f;

    for (int k0 = 0; k0 < K; k0 += BK) {
        for (int i = tid; i < BM * BK; i += 256) {
            int m = i / BK, kk = i % BK;
            int gr = row0 + m;
            As[kk][m] = (gr < M) ? A[(long)gr * K + k0 + kk] : 0.f;
        }
        for (int i = tid; i < BK * BN; i += 256) {
            int kk = i / BN, n = i % BN;
            int gc = col0 + n;
            Bs[kk][n] = (gc < N) ? B[(long)(k0 + kk) * N + gc] : 0.f;
        }
        __syncthreads();
#pragma unroll
        for (int kk = 0; kk < BK; kk++) {
            float a[TM], b[TN];
#pragma unroll
            for (int i = 0; i < TM; i++) a[i] = As[kk][ty * TM + i];
#pragma unroll
            for (int j = 0; j < TN; j++) b[j] = Bs[kk][tx * TN + j];
#pragma unroll
            for (int i = 0; i < TM; i++)
#pragma unroll
                for (int j = 0; j < TN; j++) acc[i][j] += a[i] * b[j];
        }
        __syncthreads();
    }

#pragma unroll
    for (int i = 0; i < TM; i++) {
        int gr = row0 + ty * TM + i;
        if (gr >= M) continue;
        float rs = row_scale ? row_scale[gr] : 1.f;
#pragma unroll
        for (int j = 0; j < TN; j++) {
            int gc = col0 + tx * TN + j;
            if (gc < N) {
                float v = acc[i][j] * rs;
                if (bias) v += bias[gc];
                Cmat[(long)gr * N + gc] = v;
            }
        }
    }
}

// ---------------------------------------------------------------- aggregation
// out[v,:] = relu( rs_in[v] * sum_{s in row(v)} h[s,:] + bias[:] )
// One wave per node, lane = float2 of the 128-wide feature row.
__global__ __launch_bounds__(256) void aggregate(
        const float* __restrict__ h, const int* __restrict__ csr_src,
        const int* __restrict__ row_start, const int* __restrict__ cnt_in,
        const float* __restrict__ rs_in, const float* __restrict__ bias,
        float* __restrict__ out, int nodes) {
    const int wave = threadIdx.x >> 6;
    const int lane = threadIdx.x & 63;
    const int v = blockIdx.x * 4 + wave;
    if (v >= nodes) return;
    const float2* __restrict__ h2 = (const float2*)h;
    const int s0  = row_start[v];
    const int cnt = cnt_in[v];
    float ax = 0.f, ay = 0.f;
    int i = 0;
    for (; i + 4 <= cnt; i += 4) {
        int sa = csr_src[s0 + i];
        int sb = csr_src[s0 + i + 1];
        int sc = csr_src[s0 + i + 2];
        int sd = csr_src[s0 + i + 3];
        float2 va = h2[(long)sa * 64 + lane];
        float2 vb = h2[(long)sb * 64 + lane];
        float2 vc = h2[(long)sc * 64 + lane];
        float2 vd = h2[(long)sd * 64 + lane];
        ax += (va.x + vb.x) + (vc.x + vd.x);
        ay += (va.y + vb.y) + (vc.y + vd.y);
    }
    for (; i < cnt; i++) {
        int s = csr_src[s0 + i];
        float2 vv = h2[(long)s * 64 + lane];
        ax += vv.x; ay += vv.y;
    }
    const float rs = rs_in[v];
    const float2 bb = ((const float2*)bias)[lane];
    float2 o;
    o.x = fmaxf(ax * rs + bb.x, 0.f);
    o.y = fmaxf(ay * rs + bb.y, 0.f);
    ((float2*)out)[(long)v * 64 + lane] = o;
}

// ---------------------------------------------------------------- launch
extern "C" void kernel_launch(void* const* d_in, const int* in_sizes, int n_in,
                              void* d_out, int out_size, void* d_ws, size_t ws_size,
                              hipStream_t stream) {
    const float* n_feats = (const float*)d_in[0];
    const int*   src     = (const int*)d_in[1];
    const int*   dst     = (const int*)d_in[2];
    const float* Wp      = (const float*)d_in[3];
    const float* bp      = (const float*)d_in[4];
    const float* W1      = (const float*)d_in[5];
    const float* b1      = (const float*)d_in[6];
    const float* W2      = (const float*)d_in[7];
    const float* b2      = (const float*)d_in[8];
    const float* Wc      = (const float*)d_in[9];
    const float* bc      = (const float*)d_in[10];
    float* out = (float*)d_out;
    const int E = in_sizes[1];

    // workspace layout (all 4-byte types)
    char* ws = (char*)d_ws;
    int*   cnt_out    = (int*)ws;                       // N
    int*   cnt_in     = cnt_out + NN;                   // N
    int*   cursor     = cnt_in + NN;                    // N
    int*   row_start  = cursor + NN;                    // N
    float* rs_out     = (float*)(row_start + NN);       // N
    float* rs_in      = rs_out + NN;                    // N
    int*   block_sums = (int*)(rs_in + NN);             // 256
    int*   csr_src    = block_sums + 256;               // E
    float* xbuf       = (float*)(csr_src + E);          // N*H
    float* hbuf       = xbuf + (long)NN * H;            // N*H

    const int TB = 256;
    const int NB = (NN + 255) / 256;   // 196 scan blocks
    zero_ints<<<(3 * NN + TB - 1) / TB, TB, 0, stream>>>(cnt_out, 3 * NN);
    count_deg<<<(E + TB - 1) / TB, TB, 0, stream>>>(src, dst, cnt_out, cnt_in, E);
    make_rs<<<(NN + TB - 1) / TB, TB, 0, stream>>>(cnt_out, cnt_in, rs_out, rs_in, NN);
    // parallel exclusive scan of cnt_in -> row_start
    scan_partial<<<NB, 256, 0, stream>>>(cnt_in, row_start, block_sums, NN);
    scan_sums<<<1, 256, 0, stream>>>(block_sums, NB);
    scan_add<<<NB, 256, 0, stream>>>(row_start, block_sums, NN);
    fill_csr<<<(E + TB - 1) / TB, TB, 0, stream>>>(src, dst, row_start, cursor, csr_src, E);

    const dim3 gbig(H / 64, (NN + 127) / 128);   // (2, 391)
    // projection: xbuf = n_feats @ Wp + bp
    sgemm_big<<<gbig, 256, 0, stream>>>(n_feats, Wp, bp, nullptr, xbuf, NN, H, F);
    // layer 1 GEMM: hbuf = (xbuf @ W1) * rs_out
    sgemm_big<<<gbig, 256, 0, stream>>>(xbuf, W1, nullptr, rs_out, hbuf, NN, H, H);
    // aggregate: xbuf = relu(rs_in * (A hbuf) + b1)
    aggregate<<<(NN + 3) / 4, 256, 0, stream>>>(hbuf, csr_src, row_start, cnt_in, rs_in, b1, xbuf, NN);
    // layer 2 GEMM
    sgemm_big<<<gbig, 256, 0, stream>>>(xbuf, W2, nullptr, rs_out, hbuf, NN, H, H);
    // aggregate
    aggregate<<<(NN + 3) / 4, 256, 0, stream>>>(hbuf, csr_src, row_start, cnt_in, rs_in, b2, xbuf, NN);
    // classifier: out = xbuf @ Wc + bc
    {
        dim3 grid((C + 63) / 64, (NN + 63) / 64);
        sgemm_ep<64, 64, 16, 4, 4><<<grid, 256, 0, stream>>>(xbuf, Wc, bc, nullptr, out, NN, C, H);
    }
}

// Round 4
// 379.719 us; speedup vs baseline: 2.0208x; 1.2644x over previous
//
#include <hip/hip_runtime.h>

// Problem constants (from reference setup_inputs)
constexpr int NN = 50000;   // nodes
constexpr int H  = 128;     // hidden
constexpr int F  = 256;     // input features
constexpr int C  = 40;      // classes

typedef short bf16x8 __attribute__((ext_vector_type(8)));
typedef short s16x4  __attribute__((ext_vector_type(4)));
typedef float f32x4  __attribute__((ext_vector_type(4)));

__device__ inline unsigned short f2bf(float f) {          // RNE fp32 -> bf16
    unsigned u = __float_as_uint(f);
    u += 0x7fff + ((u >> 16) & 1);
    return (unsigned short)(u >> 16);
}
__device__ inline float bf2f(unsigned short s) {
    return __uint_as_float(((unsigned)s) << 16);
}

// ---------------------------------------------------------------- utilities
__global__ void zero_ints(int* __restrict__ p, int n) {
    int i = blockIdx.x * blockDim.x + threadIdx.x;
    if (i < n) p[i] = 0;
}

__global__ void count_deg(const int* __restrict__ src, const int* __restrict__ dst,
                          int* __restrict__ cnt_out, int* __restrict__ cnt_in, int E) {
    int e = blockIdx.x * blockDim.x + threadIdx.x;
    if (e < E) {
        atomicAdd(&cnt_out[src[e]], 1);
        atomicAdd(&cnt_in[dst[e]], 1);
    }
}

__global__ void make_rs(const int* __restrict__ cnt_out, const int* __restrict__ cnt_in,
                        float* __restrict__ rs_out, float* __restrict__ rs_in, int n) {
    int i = blockIdx.x * blockDim.x + threadIdx.x;
    if (i < n) {
        rs_out[i] = rsqrtf((float)max(cnt_out[i], 1));
        rs_in[i]  = rsqrtf((float)max(cnt_in[i], 1));
    }
}

// ------------------------------------------------ parallel exclusive scan
__global__ __launch_bounds__(256) void scan_partial(
        const int* __restrict__ cnt, int* __restrict__ excl,
        int* __restrict__ block_sums, int n) {
    __shared__ int sh[256];
    const int t = threadIdx.x;
    const int i = blockIdx.x * 256 + t;
    const int v = (i < n) ? cnt[i] : 0;
    sh[t] = v;
    __syncthreads();
#pragma unroll
    for (int off = 1; off < 256; off <<= 1) {
        int u = (t >= off) ? sh[t - off] : 0;
        __syncthreads();
        sh[t] += u;
        __syncthreads();
    }
    if (i < n) excl[i] = sh[t] - v;
    if (t == 255) block_sums[blockIdx.x] = sh[255];
}

__global__ __launch_bounds__(256) void scan_sums(int* __restrict__ block_sums, int nb) {
    __shared__ int sh[256];
    const int t = threadIdx.x;
    const int v = (t < nb) ? block_sums[t] : 0;
    sh[t] = v;
    __syncthreads();
#pragma unroll
    for (int off = 1; off < 256; off <<= 1) {
        int u = (t >= off) ? sh[t - off] : 0;
        __syncthreads();
        sh[t] += u;
        __syncthreads();
    }
    if (t < nb) block_sums[t] = sh[t] - v;
}

__global__ __launch_bounds__(256) void scan_add(
        int* __restrict__ row_start, const int* __restrict__ block_sums, int n) {
    const int i = blockIdx.x * 256 + threadIdx.x;
    if (i < n) row_start[i] += block_sums[blockIdx.x];
}

__global__ void fill_csr(const int* __restrict__ src, const int* __restrict__ dst,
                         const int* __restrict__ row_start, int* __restrict__ cursor,
                         int* __restrict__ csr_src, int E) {
    int e = blockIdx.x * blockDim.x + threadIdx.x;
    if (e < E) {
        int d = dst[e];
        int pos = row_start[d] + atomicAdd(&cursor[d], 1);
        csr_src[pos] = src[e];
    }
}

// ------------------------------------------------ weight prep: transpose + hi/lo split
// W row-major [K][N] fp32 -> Bth/Btl [NP][K] bf16 (rows >= N zero-padded)
__global__ void prep_Bt(const float* __restrict__ W,
                        unsigned short* __restrict__ Bth, unsigned short* __restrict__ Btl,
                        int K, int N, int NP) {
    int i = blockIdx.x * blockDim.x + threadIdx.x;
    if (i >= NP * K) return;
    int n = i / K, k = i % K;
    float v = (n < N) ? W[(long)k * N + n] : 0.f;
    unsigned short hh = f2bf(v);
    unsigned short ll = f2bf(v - bf2f(hh));
    Bth[(long)n * K + k] = hh;
    Btl[(long)n * K + k] = ll;
}

// ------------------------------------------------ MFMA split-bf16 GEMM
// C = A(fp32,[M,K]) @ B(fp32,[K,Nout]) via hi/lo bf16 split (3 MFMA products).
// B supplied pre-transposed+split: Bth/Btl [BN][K] bf16 (BN >= Nout, zero-padded).
// grid = (1, ceil(M/64)), 256 threads (4 waves). BM=64, BK=32, wave owns BN/4 cols.
// MODE 0: outf[gr*Nout+gc] = acc + bias[gc]            (gc < Nout store mask)
// MODE 1: outh[gr*Nout+gc] = bf16(acc * row_scale[gr])
template<int MODE, int BN>
__global__ __launch_bounds__(256) void mfma_gemm(
        const float* __restrict__ A,
        const unsigned short* __restrict__ Bth, const unsigned short* __restrict__ Btl,
        const float* __restrict__ bias, const float* __restrict__ row_scale,
        float* __restrict__ outf, unsigned short* __restrict__ outh,
        int M, int Nout, int K) {
    constexpr int NT = BN / 64;               // n-tiles (16 wide) per wave
    // fragment-major LDS: [k4][row][8], +1 row pad per k4 group (quads 4 banks apart)
    __shared__ unsigned short As_h[4 * 65 * 8];
    __shared__ unsigned short As_l[4 * 65 * 8];
    __shared__ unsigned short Bs_h[4 * (BN + 1) * 8];
    __shared__ unsigned short Bs_l[4 * (BN + 1) * 8];

    const int tid  = threadIdx.x;
    const int wave = tid >> 6;
    const int lane = tid & 63;
    const int quad = lane >> 4;
    const int lr   = lane & 15;
    const int row0 = blockIdx.y * 64;
    const int wn0  = wave * (BN / 4);

    f32x4 acc[4][NT];
#pragma unroll
    for (int mt = 0; mt < 4; mt++)
#pragma unroll
        for (int nt = 0; nt < NT; nt++)
            acc[mt][nt] = (f32x4){0.f, 0.f, 0.f, 0.f};

    for (int k0 = 0; k0 < K; k0 += 32) {
        // ---- stage A tile (64 rows x 32 k fp32), split to hi/lo bf16
#pragma unroll
        for (int r = 0; r < 2; r++) {
            int c   = tid + 256 * r;          // 0..511
            int row = c >> 3;                 // 0..63
            int k4f = c & 7;                  // float4 index along k
            int gr  = row0 + row;
            float4 v = make_float4(0.f, 0.f, 0.f, 0.f);
            if (gr < M) v = *(const float4*)&A[(long)gr * K + k0 + k4f * 4];
            unsigned short h0 = f2bf(v.x), h1 = f2bf(v.y), h2 = f2bf(v.z), h3 = f2bf(v.w);
            unsigned short l0 = f2bf(v.x - bf2f(h0));
            unsigned short l1 = f2bf(v.y - bf2f(h1));
            unsigned short l2 = f2bf(v.z - bf2f(h2));
            unsigned short l3 = f2bf(v.w - bf2f(h3));
            int base = (k4f >> 1) * 520 + row * 8 + (k4f & 1) * 4;
            s16x4 hv; hv[0] = (short)h0; hv[1] = (short)h1; hv[2] = (short)h2; hv[3] = (short)h3;
            s16x4 lv; lv[0] = (short)l0; lv[1] = (short)l1; lv[2] = (short)l2; lv[3] = (short)l3;
            *(s16x4*)&As_h[base] = hv;
            *(s16x4*)&As_l[base] = lv;
        }
        // ---- stage B tile (BN rows x 32 k bf16, already split)
        for (int c = tid; c < BN * 4; c += 256) {
            int n  = c >> 2;
            int k4 = c & 3;
            long off = (long)n * K + k0 + k4 * 8;
            uint4 vh = *(const uint4*)&Bth[off];
            uint4 vl = *(const uint4*)&Btl[off];
            int bbase = k4 * (BN + 1) * 8 + n * 8;
            *(uint4*)&Bs_h[bbase] = vh;
            *(uint4*)&Bs_l[bbase] = vl;
        }
        __syncthreads();

        // ---- fragments + MFMA (covers full K=32 per tile)
        bf16x8 ah[4], al[4], bh[NT], bl[NT];
#pragma unroll
        for (int mt = 0; mt < 4; mt++) {
            int ab = quad * 520 + (mt * 16 + lr) * 8;
            ah[mt] = *(const bf16x8*)&As_h[ab];
            al[mt] = *(const bf16x8*)&As_l[ab];
        }
#pragma unroll
        for (int nt = 0; nt < NT; nt++) {
            int bb = quad * (BN + 1) * 8 + (wn0 + nt * 16 + lr) * 8;
            bh[nt] = *(const bf16x8*)&Bs_h[bb];
            bl[nt] = *(const bf16x8*)&Bs_l[bb];
        }
#pragma unroll
        for (int mt = 0; mt < 4; mt++)
#pragma unroll
            for (int nt = 0; nt < NT; nt++) {
                acc[mt][nt] = __builtin_amdgcn_mfma_f32_16x16x32_bf16(ah[mt], bh[nt], acc[mt][nt], 0, 0, 0);
                acc[mt][nt] = __builtin_amdgcn_mfma_f32_16x16x32_bf16(al[mt], bh[nt], acc[mt][nt], 0, 0, 0);
                acc[mt][nt] = __builtin_amdgcn_mfma_f32_16x16x32_bf16(ah[mt], bl[nt], acc[mt][nt], 0, 0, 0);
            }
        __syncthreads();
    }

    // ---- epilogue.  D layout: col = lane&15, row = quad*4 + reg.
#pragma unroll
    for (int mt = 0; mt < 4; mt++) {
#pragma unroll
        for (int nt = 0; nt < NT; nt++) {
            int gc = wn0 + nt * 16 + lr;
#pragma unroll
            for (int r = 0; r < 4; r++) {
                int gr = row0 + mt * 16 + quad * 4 + r;
                if (gr >= M) continue;
                float v = acc[mt][nt][r];
                if (MODE == 0) {
                    if (gc < Nout) outf[(long)gr * Nout + gc] = v + bias[gc];
                } else {
                    v *= row_scale[gr];
                    outh[(long)gr * Nout + gc] = f2bf(v);
                }
            }
        }
    }
}

// ---------------------------------------------------------------- aggregation (bf16 h)
// out[v,:] = relu( rs_in[v] * sum_{s in row(v)} h[s,:] + bias[:] )
// h packed bf16 [M][128] -> read as uint [M][64]; one wave per node.
__global__ __launch_bounds__(256) void aggregate_bf16(
        const unsigned int* __restrict__ h, const int* __restrict__ csr_src,
        const int* __restrict__ row_start, const int* __restrict__ cnt_in,
        const float* __restrict__ rs_in, const float* __restrict__ bias,
        float* __restrict__ out, int nodes) {
    const int wave = threadIdx.x >> 6;
    const int lane = threadIdx.x & 63;
    const int v = blockIdx.x * 4 + wave;
    if (v >= nodes) return;
    const int s0  = row_start[v];
    const int cnt = cnt_in[v];
    float ax = 0.f, ay = 0.f;
    int i = 0;
    for (; i + 4 <= cnt; i += 4) {
        int sa = csr_src[s0 + i];
        int sb = csr_src[s0 + i + 1];
        int sc = csr_src[s0 + i + 2];
        int sd = csr_src[s0 + i + 3];
        unsigned ua = h[(long)sa * 64 + lane];
        unsigned ub = h[(long)sb * 64 + lane];
        unsigned uc = h[(long)sc * 64 + lane];
        unsigned ud = h[(long)sd * 64 + lane];
        ax += __uint_as_float(ua << 16) + __uint_as_float(ub << 16)
            + __uint_as_float(uc << 16) + __uint_as_float(ud << 16);
        ay += __uint_as_float(ua & 0xffff0000u) + __uint_as_float(ub & 0xffff0000u)
            + __uint_as_float(uc & 0xffff0000u) + __uint_as_float(ud & 0xffff0000u);
    }
    for (; i < cnt; i++) {
        int s = csr_src[s0 + i];
        unsigned u = h[(long)s * 64 + lane];
        ax += __uint_as_float(u << 16);
        ay += __uint_as_float(u & 0xffff0000u);
    }
    const float rs = rs_in[v];
    const float2 bb = ((const float2*)bias)[lane];
    float2 o;
    o.x = fmaxf(ax * rs + bb.x, 0.f);
    o.y = fmaxf(ay * rs + bb.y, 0.f);
    ((float2*)out)[(long)v * 64 + lane] = o;
}

// ---------------------------------------------------------------- launch
extern "C" void kernel_launch(void* const* d_in, const int* in_sizes, int n_in,
                              void* d_out, int out_size, void* d_ws, size_t ws_size,
                              hipStream_t stream) {
    const float* n_feats = (const float*)d_in[0];
    const int*   src     = (const int*)d_in[1];
    const int*   dst     = (const int*)d_in[2];
    const float* Wp      = (const float*)d_in[3];
    const float* bp      = (const float*)d_in[4];
    const float* W1      = (const float*)d_in[5];
    const float* b1      = (const float*)d_in[6];
    const float* W2      = (const float*)d_in[7];
    const float* b2      = (const float*)d_in[8];
    const float* Wc      = (const float*)d_in[9];
    const float* bc      = (const float*)d_in[10];
    float* out = (float*)d_out;
    const int E = in_sizes[1];

    // workspace layout (16B-aligned sections)
    char* ws = (char*)d_ws;
    float*          xbuf  = (float*)ws;                            // NN*128 fp32
    unsigned short* hbuf  = (unsigned short*)(xbuf + (long)NN * H); // NN*128 bf16
    unsigned short* bt_ph = hbuf + (long)NN * H;                   // 128*256
    unsigned short* bt_pl = bt_ph + 128 * 256;
    unsigned short* bt_1h = bt_pl + 128 * 256;                     // 128*128
    unsigned short* bt_1l = bt_1h + 128 * 128;
    unsigned short* bt_2h = bt_1l + 128 * 128;
    unsigned short* bt_2l = bt_2h + 128 * 128;
    unsigned short* bt_ch = bt_2l + 128 * 128;                     // 64*128
    unsigned short* bt_cl = bt_ch + 64 * 128;
    int*   cnt_out    = (int*)(bt_cl + 64 * 128);                  // N
    int*   cnt_in     = cnt_out + NN;
    int*   cursor     = cnt_in + NN;
    int*   row_start  = cursor + NN;
    float* rs_out     = (float*)(row_start + NN);
    float* rs_in      = rs_out + NN;
    int*   block_sums = (int*)(rs_in + NN);                        // 256
    int*   csr_src    = block_sums + 256;                          // E

    const int TB = 256;
    const int NB = (NN + 255) / 256;
    // graph structure
    zero_ints<<<(3 * NN + TB - 1) / TB, TB, 0, stream>>>(cnt_out, 3 * NN);
    count_deg<<<(E + TB - 1) / TB, TB, 0, stream>>>(src, dst, cnt_out, cnt_in, E);
    make_rs<<<(NN + TB - 1) / TB, TB, 0, stream>>>(cnt_out, cnt_in, rs_out, rs_in, NN);
    scan_partial<<<NB, 256, 0, stream>>>(cnt_in, row_start, block_sums, NN);
    scan_sums<<<1, 256, 0, stream>>>(block_sums, NB);
    scan_add<<<NB, 256, 0, stream>>>(row_start, block_sums, NN);
    fill_csr<<<(E + TB - 1) / TB, TB, 0, stream>>>(src, dst, row_start, cursor, csr_src, E);
    // weight prep (transpose + hi/lo split)
    prep_Bt<<<(128 * F + TB - 1) / TB, TB, 0, stream>>>(Wp, bt_ph, bt_pl, F, H, 128);
    prep_Bt<<<(128 * H + TB - 1) / TB, TB, 0, stream>>>(W1, bt_1h, bt_1l, H, H, 128);
    prep_Bt<<<(128 * H + TB - 1) / TB, TB, 0, stream>>>(W2, bt_2h, bt_2l, H, H, 128);
    prep_Bt<<<(64 * H + TB - 1) / TB, TB, 0, stream>>>(Wc, bt_ch, bt_cl, H, C, 64);

    const dim3 gg(1, (NN + 63) / 64);   // 782 blocks
    // projection: xbuf = n_feats @ Wp + bp            (fp32 out)
    mfma_gemm<0, 128><<<gg, 256, 0, stream>>>(n_feats, bt_ph, bt_pl, bp, nullptr,
                                              xbuf, nullptr, NN, H, F);
    // layer 1 GEMM: hbuf = bf16((xbuf @ W1) * rs_out)
    mfma_gemm<1, 128><<<gg, 256, 0, stream>>>(xbuf, bt_1h, bt_1l, nullptr, rs_out,
                                              nullptr, hbuf, NN, H, H);
    aggregate_bf16<<<(NN + 3) / 4, 256, 0, stream>>>((const unsigned int*)hbuf, csr_src,
                                                     row_start, cnt_in, rs_in, b1, xbuf, NN);
    // layer 2
    mfma_gemm<1, 128><<<gg, 256, 0, stream>>>(xbuf, bt_2h, bt_2l, nullptr, rs_out,
                                              nullptr, hbuf, NN, H, H);
    aggregate_bf16<<<(NN + 3) / 4, 256, 0, stream>>>((const unsigned int*)hbuf, csr_src,
                                                     row_start, cnt_in, rs_in, b2, xbuf, NN);
    // classifier: out = xbuf @ Wc + bc  (B padded to 64 cols, store-masked to 40)
    mfma_gemm<0, 64><<<gg, 256, 0, stream>>>(xbuf, bt_ch, bt_cl, bc, nullptr,
                                             out, nullptr, NN, C, H);
}